// Round 4
// baseline (713.283 us; speedup 1.0000x reference)
//
#include <hip/hip_runtime.h>

// ---------------------------------------------------------------------------
// ScaledDotProductAttention: q=x@Wq^T, k=x@Wk^T, S=q@k^T*1/32 (masked),
// softmax fp32, ctx = W@V.  All GEMMs: bf16 MFMA 16x16x32, m97 128x128xBK64
// structure with global_load_lds dwordx4 staging.
// ---------------------------------------------------------------------------

typedef __bf16 bf16x8 __attribute__((ext_vector_type(8)));
typedef float  f32x4  __attribute__((ext_vector_type(4)));

#define AS1 __attribute__((address_space(1)))
#define AS3 __attribute__((address_space(3)))

__device__ __forceinline__ ushort f2bf(float f) {
  union { float f; unsigned u; } v; v.f = f;
  unsigned u = v.u;
  unsigned r = (u + 0x7FFFu + ((u >> 16) & 1u)) >> 16;  // RNE
  return (ushort)r;
}

constexpr float SCORE_SCALE = 0.03125f;  // 1/sqrt(1024)

// ---------------------------------------------------------------------------
// Generic C = A @ B^T, A[M,K] bf16 row-major, B[N,K] bf16 row-major.
// MODE 0: C bf16.  MODE 1: C fp32 = acc*SCALE, mask[n]==0 -> -inf.
// MODE 2: C fp32 plain.
// Block: 256 thr (4 waves), tile 128x128, BK=64; wave -> 64x64 (4x4 frags).
// ---------------------------------------------------------------------------
template <int MODE>
__global__ __launch_bounds__(256, 2)
void gemm_bt(const ushort* __restrict__ Ag, const ushort* __restrict__ Bg,
             void* __restrict__ Cv, const int* __restrict__ mask,
             int N, int K, long sA, long sB, long sC, int sMask)
{
  __shared__ ushort As[128 * 64];   // 16 KiB, row stride 64 bf16 = 128 B
  __shared__ ushort Bs[128 * 64];

  const int b = blockIdx.z;
  const ushort* Ab = Ag + (long)b * sA;
  const ushort* Bb = Bg + (long)b * sB;

  const int tid  = threadIdx.x;
  const int lane = tid & 63;
  const int wid  = tid >> 6;          // 0..3
  const int wr   = wid >> 1;          // wave row (0..1)
  const int wc   = wid & 1;           // wave col (0..1)
  const int m0   = blockIdx.y * 128;
  const int n0   = blockIdx.x * 128;

  // staging: wave-uniform LDS dest + lane*16B  ->  lane l covers
  // row = rowblk + l/8, k-offset = (l%8)*8 of the 128x64 tile
  const int srow = lane >> 3;
  const int skof = (lane & 7) * 8;

  const int laneQuad = lane >> 4;     // 0..3
  const int lane15   = lane & 15;
  const int fko      = laneQuad * 8;  // fragment k offset (8 bf16 = 16 B)

  f32x4 acc[4][4];
#pragma unroll
  for (int i = 0; i < 4; ++i)
#pragma unroll
    for (int j = 0; j < 4; ++j) acc[i][j] = (f32x4){0.f, 0.f, 0.f, 0.f};

  for (int kt = 0; kt < K; kt += 64) {
#pragma unroll
    for (int r = 0; r < 4; ++r) {
      const int rowblk = (r * 4 + wid) * 8;  // wave-uniform
      const ushort* ga = Ab + (long)(m0 + rowblk + srow) * K + (kt + skof);
      __builtin_amdgcn_global_load_lds((const AS1 void*)ga,
                                       (AS3 void*)(As + rowblk * 64), 16, 0, 0);
      const ushort* gb = Bb + (long)(n0 + rowblk + srow) * K + (kt + skof);
      __builtin_amdgcn_global_load_lds((const AS1 void*)gb,
                                       (AS3 void*)(Bs + rowblk * 64), 16, 0, 0);
    }
    __syncthreads();   // compiler drains vmcnt before s_barrier -> LDS ready

#pragma unroll
    for (int kk = 0; kk < 64; kk += 32) {
      bf16x8 af[4], bfr[4];
#pragma unroll
      for (int mi = 0; mi < 4; ++mi)
        af[mi] = *(const bf16x8*)(As + (wr * 64 + mi * 16 + lane15) * 64 + kk + fko);
#pragma unroll
      for (int ni = 0; ni < 4; ++ni)
        bfr[ni] = *(const bf16x8*)(Bs + (wc * 64 + ni * 16 + lane15) * 64 + kk + fko);
#pragma unroll
      for (int mi = 0; mi < 4; ++mi)
#pragma unroll
        for (int ni = 0; ni < 4; ++ni)
          acc[mi][ni] = __builtin_amdgcn_mfma_f32_16x16x32_bf16(
              af[mi], bfr[ni], acc[mi][ni], 0, 0, 0);
    }
    __syncthreads();
  }

  // epilogue: D row = (lane>>4)*4 + r, col = lane&15  [measured m89/m91]
  const int rbase = laneQuad * 4;
  if constexpr (MODE == 0) {
    ushort* C = (ushort*)Cv + (long)b * sC;
#pragma unroll
    for (int mi = 0; mi < 4; ++mi) {
      const int r0 = m0 + wr * 64 + mi * 16 + rbase;
#pragma unroll
      for (int ni = 0; ni < 4; ++ni) {
        const int col = n0 + wc * 64 + ni * 16 + lane15;
#pragma unroll
        for (int r = 0; r < 4; ++r)
          C[(long)(r0 + r) * N + col] = f2bf(acc[mi][ni][r]);
      }
    }
  } else if constexpr (MODE == 1) {
    float* C = (float*)Cv + (long)b * sC;
    const int* mb = mask + (long)b * sMask;
    int   mk[4]; int coln[4];
#pragma unroll
    for (int ni = 0; ni < 4; ++ni) {
      coln[ni] = n0 + wc * 64 + ni * 16 + lane15;
      mk[ni]   = mb[coln[ni]];
    }
    const float ninf = -__builtin_inff();
#pragma unroll
    for (int mi = 0; mi < 4; ++mi) {
      const int r0 = m0 + wr * 64 + mi * 16 + rbase;
#pragma unroll
      for (int ni = 0; ni < 4; ++ni)
#pragma unroll
        for (int r = 0; r < 4; ++r)
          C[(long)(r0 + r) * N + coln[ni]] =
              mk[ni] ? acc[mi][ni][r] * SCORE_SCALE : ninf;
    }
  } else {
    float* C = (float*)Cv + (long)b * sC;
#pragma unroll
    for (int mi = 0; mi < 4; ++mi) {
      const int r0 = m0 + wr * 64 + mi * 16 + rbase;
#pragma unroll
      for (int ni = 0; ni < 4; ++ni) {
        const int col = n0 + wc * 64 + ni * 16 + lane15;
#pragma unroll
        for (int r = 0; r < 4; ++r)
          C[(long)(r0 + r) * N + col] = acc[mi][ni][r];
      }
    }
  }
}

// ---------------------------------------------------------------------------
// fp32 -> bf16 elementwise (float4 in, ushort4 out)
// ---------------------------------------------------------------------------
__global__ __launch_bounds__(256)
void cvt_f32_bf16(const float* __restrict__ in, ushort* __restrict__ out, int n4)
{
  const int i = blockIdx.x * 256 + threadIdx.x;
  if (i >= n4) return;
  float4 v = ((const float4*)in)[i];
  ushort4 o;
  o.x = f2bf(v.x); o.y = f2bf(v.y); o.z = f2bf(v.z); o.w = f2bf(v.w);
  ((ushort4*)out)[i] = o;
}

// ---------------------------------------------------------------------------
// Vt[b][d][k] = bf16(V[b][k][d]); 64x64 LDS tile, pad 65 (conflict-free)
// grid (LK/64, DV/64, B), 256 threads
// ---------------------------------------------------------------------------
__global__ __launch_bounds__(256)
void transpose_v(const float* __restrict__ V, ushort* __restrict__ Vt)
{
  __shared__ ushort t[64][65];
  const int b = blockIdx.z;
  const float* Vb  = V  + (long)b * 2048 * 1024;
  ushort*      Vtb = Vt + (long)b * 1024 * 2048;
  const int k0 = blockIdx.x * 64, d0 = blockIdx.y * 64;
  const int c  = threadIdx.x & 63;
  const int r4 = threadIdx.x >> 6;
#pragma unroll
  for (int i = 0; i < 64; i += 4)
    t[i + r4][c] = f2bf(Vb[(long)(k0 + i + r4) * 1024 + d0 + c]);
  __syncthreads();
#pragma unroll
  for (int i = 0; i < 64; i += 4)
    Vtb[(long)(d0 + i + r4) * 2048 + k0 + c] = t[c][i + r4];
}

// ---------------------------------------------------------------------------
// Row softmax over 2048 fp32 (in-place, d_out region) + bf16 copy to ws.
// One block per row, 256 threads x 8 elements.
// ---------------------------------------------------------------------------
__global__ __launch_bounds__(256)
void softmax_rows(float* __restrict__ S, ushort* __restrict__ Wb)
{
  const long row = blockIdx.x;
  float*  Sr = S  + row * 2048;
  ushort* Wr = Wb + row * 2048;
  const int tid = threadIdx.x;

  float4 a = *(const float4*)(Sr + tid * 4);
  float4 c = *(const float4*)(Sr + 1024 + tid * 4);

  float m = fmaxf(fmaxf(fmaxf(a.x, a.y), fmaxf(a.z, a.w)),
                  fmaxf(fmaxf(c.x, c.y), fmaxf(c.z, c.w)));
#pragma unroll
  for (int off = 32; off > 0; off >>= 1) m = fmaxf(m, __shfl_xor(m, off, 64));

  __shared__ float red[8];
  const int wid = tid >> 6, lane = tid & 63;
  if (lane == 0) red[wid] = m;
  __syncthreads();
  m = fmaxf(fmaxf(red[0], red[1]), fmaxf(red[2], red[3]));

  float e[8];
  e[0] = __expf(a.x - m); e[1] = __expf(a.y - m);
  e[2] = __expf(a.z - m); e[3] = __expf(a.w - m);
  e[4] = __expf(c.x - m); e[5] = __expf(c.y - m);
  e[6] = __expf(c.z - m); e[7] = __expf(c.w - m);
  float s = e[0] + e[1] + e[2] + e[3] + e[4] + e[5] + e[6] + e[7];
#pragma unroll
  for (int off = 32; off > 0; off >>= 1) s += __shfl_xor(s, off, 64);
  if (lane == 0) red[4 + wid] = s;
  __syncthreads();
  s = red[4] + red[5] + red[6] + red[7];

  const float inv = 1.0f / s;
  float4 o0 = make_float4(e[0] * inv, e[1] * inv, e[2] * inv, e[3] * inv);
  float4 o1 = make_float4(e[4] * inv, e[5] * inv, e[6] * inv, e[7] * inv);
  *(float4*)(Sr + tid * 4)        = o0;
  *(float4*)(Sr + 1024 + tid * 4) = o1;
  ushort4 w0, w1;
  w0.x = f2bf(o0.x); w0.y = f2bf(o0.y); w0.z = f2bf(o0.z); w0.w = f2bf(o0.w);
  w1.x = f2bf(o1.x); w1.y = f2bf(o1.y); w1.z = f2bf(o1.z); w1.w = f2bf(o1.w);
  *(ushort4*)(Wr + tid * 4)        = w0;
  *(ushort4*)(Wr + 1024 + tid * 4) = w1;
}

// ---------------------------------------------------------------------------
// Workspace layout (bytes). Wb (bf16 attn weights, 64 MiB) aliases the
// converted-query/key region, which is dead after the projection GEMMs.
// Total ws required: 171,966,464 bytes (~164 MiB).
// ---------------------------------------------------------------------------
constexpr size_t SZ_XB  = 16384UL * 1024 * 2;        // 32 MiB
constexpr size_t OFF_QB = 0;
constexpr size_t OFF_KB = SZ_XB;
constexpr size_t OFF_WQ = 2 * SZ_XB;                 // 2 MiB
constexpr size_t OFF_WK = OFF_WQ + 1024UL * 1024 * 2;
constexpr size_t OFF_QP = OFF_WK + 1024UL * 1024 * 2;
constexpr size_t OFF_KP = OFF_QP + SZ_XB;
constexpr size_t OFF_VT = OFF_KP + SZ_XB;
constexpr size_t OFF_WB = 0;                          // aliases QB+KB

extern "C" void kernel_launch(void* const* d_in, const int* in_sizes, int n_in,
                              void* d_out, int out_size, void* d_ws, size_t ws_size,
                              hipStream_t stream)
{
  (void)in_sizes; (void)n_in; (void)out_size; (void)ws_size;

  const float* query = (const float*)d_in[0];  // [8,2048,1024]
  const float* key   = (const float*)d_in[1];  // [8,2048,1024]
  const float* value = (const float*)d_in[2];  // [8,2048,1024]
  const int*   mask  = (const int*)d_in[3];    // [8,1,2048]
  const float* Wq    = (const float*)d_in[4];  // [1024,1024]
  const float* Wk    = (const float*)d_in[5];  // [1024,1024]

  float* out_cxt = (float*)d_out;                      // [8,2048,1024]
  float* out_w   = out_cxt + 8L * 2048 * 1024;         // [8,2048,2048]

  char* ws = (char*)d_ws;
  ushort* qb  = (ushort*)(ws + OFF_QB);
  ushort* kb  = (ushort*)(ws + OFF_KB);
  ushort* wqb = (ushort*)(ws + OFF_WQ);
  ushort* wkb = (ushort*)(ws + OFF_WK);
  ushort* Qp  = (ushort*)(ws + OFF_QP);
  ushort* Kp  = (ushort*)(ws + OFF_KP);
  ushort* Vt  = (ushort*)(ws + OFF_VT);
  ushort* Wb  = (ushort*)(ws + OFF_WB);

  // 1) casts + V transpose
  cvt_f32_bf16<<<16384, 256, 0, stream>>>(query, qb, 4194304);
  cvt_f32_bf16<<<16384, 256, 0, stream>>>(key,   kb, 4194304);
  cvt_f32_bf16<<<1024,  256, 0, stream>>>(Wq, wqb, 262144);
  cvt_f32_bf16<<<1024,  256, 0, stream>>>(Wk, wkb, 262144);
  transpose_v<<<dim3(32, 16, 8), 256, 0, stream>>>(value, Vt);

  // 2) projections: [16384,1024] @ [1024,1024]^T -> bf16
  gemm_bt<0><<<dim3(8, 128, 1), 256, 0, stream>>>(qb, wqb, Qp, nullptr,
                                                  1024, 1024, 0, 0, 0, 0);
  gemm_bt<0><<<dim3(8, 128, 1), 256, 0, stream>>>(kb, wkb, Kp, nullptr,
                                                  1024, 1024, 0, 0, 0, 0);

  // 3) scores: per-batch [2048,1024] @ [2048,1024]^T * 1/32, masked -> fp32
  //    written directly into the attn_weight output region
  gemm_bt<1><<<dim3(16, 16, 8), 256, 0, stream>>>(Qp, Kp, out_w, mask,
                                                  2048, 1024,
                                                  2048L * 1024, 2048L * 1024,
                                                  2048L * 2048, 2048);

  // 4) softmax rows (normalizes out_w in place, emits bf16 weights to ws)
  softmax_rows<<<16384, 256, 0, stream>>>(out_w, Wb);

  // 5) ctx: per-batch [2048,2048] @ Vt[1024,2048]^T -> fp32
  gemm_bt<2><<<dim3(8, 16, 8), 256, 0, stream>>>(Wb, Vt, out_cxt, nullptr,
                                                 1024, 2048,
                                                 2048L * 2048, 1024L * 2048,
                                                 2048L * 1024, 0);
}

// Round 5
// 640.375 us; speedup vs baseline: 1.1139x; 1.1139x over previous
//
#include <hip/hip_runtime.h>

// ---------------------------------------------------------------------------
// ScaledDotProductAttention: q=x@Wq^T, k=x@Wk^T, S=q@k^T*1/32 (masked),
// softmax fp32, ctx = W@V.
// GEMM: bf16 MFMA 16x16x32, 256x256 tile, BK=64, 8 waves, double-buffered
// LDS with counted vmcnt(8) prefetch (raw s_barrier, no __syncthreads drain),
// T2 XOR-chunk swizzle (pre-swizzled global source + swizzled ds_read),
// T5 setprio, T1 XCD-chunked block swizzle.
// ---------------------------------------------------------------------------

typedef __bf16 bf16x8 __attribute__((ext_vector_type(8)));
typedef float  f32x4  __attribute__((ext_vector_type(4)));

#define AS1 __attribute__((address_space(1)))
#define AS3 __attribute__((address_space(3)))

__device__ __forceinline__ ushort f2bf(float f) {
  union { float f; unsigned u; } v; v.f = f;
  unsigned u = v.u;
  unsigned r = (u + 0x7FFFu + ((u >> 16) & 1u)) >> 16;  // RNE
  return (ushort)r;
}

constexpr float SCORE_SCALE = 0.03125f;  // 1/sqrt(1024)

// ---------------------------------------------------------------------------
// C = A @ B^T, A[M,K] bf16 row-major, B[N,K] bf16 row-major.
// MODE 0: C bf16.  MODE 1: C fp32 = acc*SCALE, mask[n]==0 -> -inf.
// MODE 2: C fp32 plain.
// Requires M%256==0, N%256==0, K%64==0, gridDim product %8==0 (for swizzle).
// ---------------------------------------------------------------------------
template <int MODE>
__global__ __launch_bounds__(512, 2)
void gemm_bt(const ushort* __restrict__ Ag, const ushort* __restrict__ Bg,
             void* __restrict__ Cv, const int* __restrict__ mask,
             int N, int K, long sA, long sB, long sC, int sMask)
{
  __shared__ ushort As[2][256 * 64];   // 2 x 32 KiB
  __shared__ ushort Bs[2][256 * 64];   // 2 x 32 KiB   (total 128 KiB)

  // ---- T1: XCD-chunked bijective block swizzle (nwg % 8 == 0 for our grids)
  const int nx = gridDim.x, ny = gridDim.y, nz = gridDim.z;
  const long nwg = (long)nx * ny * nz;
  long flat = blockIdx.x + (long)nx * (blockIdx.y + (long)ny * blockIdx.z);
  int bx = blockIdx.x, by = blockIdx.y, bz = blockIdx.z;
  if ((nwg & 7) == 0) {
    const long cpx = nwg >> 3;
    flat = (flat & 7) * cpx + (flat >> 3);
    bx = (int)(flat % nx);
    by = (int)((flat / nx) % ny);
    bz = (int)(flat / ((long)nx * ny));
  }
  const int m0 = by * 256;
  const int n0 = bx * 256;

  const ushort* Ab = Ag + (long)bz * sA;
  const ushort* Bb = Bg + (long)bz * sB;

  const int tid  = threadIdx.x;
  const int lane = tid & 63;
  const int wid  = tid >> 6;          // 0..7
  const int wm   = wid >> 2;          // 0..1 -> 128-row half
  const int wn   = wid & 3;           // 0..3 -> 64-col quarter
  const int l15  = lane & 15;
  const int lq   = lane >> 4;         // 0..3

  // ---- staging precompute: 4 loads/thread per matrix per K-tile.
  // linear chunk idx = j*512 + tid -> LDS row = idx>>3, phys chunk = idx&7.
  // T2: LDS phys chunk pc holds logical chunk pc ^ (row&7)  (involution),
  // achieved by loading global chunk (idx&7)^(row&7) into linear dest.
  long gAoff[4], gBoff[4];
  int  ldsoff[4];
#pragma unroll
  for (int j = 0; j < 4; ++j) {
    const int idx = j * 512 + tid;
    const int row = idx >> 3;
    const int lc  = (idx & 7) ^ (row & 7);
    gAoff[j]  = (long)(m0 + row) * K + lc * 8;
    gBoff[j]  = (long)(n0 + row) * K + lc * 8;
    ldsoff[j] = (j * 512 + wid * 64) * 8;   // wave-uniform, lanes add 16B each
  }

  f32x4 acc[8][4];
#pragma unroll
  for (int i = 0; i < 8; ++i)
#pragma unroll
    for (int j = 0; j < 4; ++j) acc[i][j] = (f32x4){0.f, 0.f, 0.f, 0.f};

  const int nt = K >> 6;

  // stage tile 0 into buf 0
#pragma unroll
  for (int j = 0; j < 4; ++j)
    __builtin_amdgcn_global_load_lds((const AS1 void*)(Ab + gAoff[j]),
                                     (AS3 void*)(&As[0][ldsoff[j]]), 16, 0, 0);
#pragma unroll
  for (int j = 0; j < 4; ++j)
    __builtin_amdgcn_global_load_lds((const AS1 void*)(Bb + gBoff[j]),
                                     (AS3 void*)(&Bs[0][ldsoff[j]]), 16, 0, 0);

  const int arow0 = wm * 128 + l15;
  const int brow0 = wn * 64 + l15;

  for (int t = 0; t < nt; ++t) {
    const ushort* Abuf = As[t & 1];
    const ushort* Bbuf = Bs[t & 1];

    if (t + 1 < nt) {
      // issue next tile's loads FIRST, then wait only for the current tile's
      const long ko = (long)(t + 1) * 64;
      const int  nb = (t + 1) & 1;
#pragma unroll
      for (int j = 0; j < 4; ++j)
        __builtin_amdgcn_global_load_lds((const AS1 void*)(Ab + gAoff[j] + ko),
                                         (AS3 void*)(&As[nb][ldsoff[j]]), 16, 0, 0);
#pragma unroll
      for (int j = 0; j < 4; ++j)
        __builtin_amdgcn_global_load_lds((const AS1 void*)(Bb + gBoff[j] + ko),
                                         (AS3 void*)(&Bs[nb][ldsoff[j]]), 16, 0, 0);
      asm volatile("s_waitcnt vmcnt(8)" ::: "memory");   // t's 8 landed, t+1's in flight
    } else {
      asm volatile("s_waitcnt vmcnt(0)" ::: "memory");   // tail: drain
    }
    __builtin_amdgcn_sched_barrier(0);
    __builtin_amdgcn_s_barrier();          // raw barrier: no vmcnt(0) drain
    __builtin_amdgcn_sched_barrier(0);

#pragma unroll
    for (int kk = 0; kk < 2; ++kk) {
      bf16x8 bfr[4];
#pragma unroll
      for (int ni = 0; ni < 4; ++ni) {
        const int row = brow0 + ni * 16;
        const int pc  = (kk * 4 + lq) ^ (row & 7);
        bfr[ni] = *(const bf16x8*)(Bbuf + row * 64 + pc * 8);
      }
      __builtin_amdgcn_s_setprio(1);
#pragma unroll
      for (int mi = 0; mi < 8; ++mi) {
        const int row = arow0 + mi * 16;
        const int pc  = (kk * 4 + lq) ^ (row & 7);
        const bf16x8 a = *(const bf16x8*)(Abuf + row * 64 + pc * 8);
#pragma unroll
        for (int ni = 0; ni < 4; ++ni)
          acc[mi][ni] = __builtin_amdgcn_mfma_f32_16x16x32_bf16(
              a, bfr[ni], acc[mi][ni], 0, 0, 0);
      }
      __builtin_amdgcn_s_setprio(0);
    }
    __builtin_amdgcn_sched_barrier(0);
    __builtin_amdgcn_s_barrier();          // all waves done reading buf t&1
  }

  // ---- epilogue: D row = (lane>>4)*4 + r, col = lane&15 [m89/m91]
  const int rbase = lq * 4;
  if constexpr (MODE == 0) {
    ushort* C = (ushort*)Cv + (long)bz * sC;
#pragma unroll
    for (int mi = 0; mi < 8; ++mi) {
      const int r0 = m0 + wm * 128 + mi * 16 + rbase;
#pragma unroll
      for (int ni = 0; ni < 4; ++ni) {
        const int col = n0 + wn * 64 + ni * 16 + l15;
#pragma unroll
        for (int r = 0; r < 4; ++r)
          C[(long)(r0 + r) * N + col] = f2bf(acc[mi][ni][r]);
      }
    }
  } else if constexpr (MODE == 1) {
    float* C = (float*)Cv + (long)bz * sC;
    const int* mb = mask + (long)bz * sMask;
    int coln[4], mk[4];
#pragma unroll
    for (int ni = 0; ni < 4; ++ni) {
      coln[ni] = n0 + wn * 64 + ni * 16 + l15;
      mk[ni]   = mb[coln[ni]];
    }
    const float ninf = -__builtin_inff();
#pragma unroll
    for (int mi = 0; mi < 8; ++mi) {
      const int r0 = m0 + wm * 128 + mi * 16 + rbase;
#pragma unroll
      for (int ni = 0; ni < 4; ++ni)
#pragma unroll
        for (int r = 0; r < 4; ++r)
          C[(long)(r0 + r) * N + coln[ni]] =
              mk[ni] ? acc[mi][ni][r] * SCORE_SCALE : ninf;
    }
  } else {
    float* C = (float*)Cv + (long)bz * sC;
#pragma unroll
    for (int mi = 0; mi < 8; ++mi) {
      const int r0 = m0 + wm * 128 + mi * 16 + rbase;
#pragma unroll
      for (int ni = 0; ni < 4; ++ni) {
        const int col = n0 + wn * 64 + ni * 16 + l15;
#pragma unroll
        for (int r = 0; r < 4; ++r)
          C[(long)(r0 + r) * N + col] = acc[mi][ni][r];
      }
    }
  }
}

// ---------------------------------------------------------------------------
// fp32 -> bf16 elementwise (float4 in, ushort4 out)
// ---------------------------------------------------------------------------
__global__ __launch_bounds__(256)
void cvt_f32_bf16(const float* __restrict__ in, ushort* __restrict__ out, int n4)
{
  const int i = blockIdx.x * 256 + threadIdx.x;
  if (i >= n4) return;
  float4 v = ((const float4*)in)[i];
  ushort4 o;
  o.x = f2bf(v.x); o.y = f2bf(v.y); o.z = f2bf(v.z); o.w = f2bf(v.w);
  ((ushort4*)out)[i] = o;
}

// ---------------------------------------------------------------------------
// Vt[b][d][k] = bf16(V[b][k][d]); 64x64 LDS tile, pad 65 (conflict-free)
// ---------------------------------------------------------------------------
__global__ __launch_bounds__(256)
void transpose_v(const float* __restrict__ V, ushort* __restrict__ Vt)
{
  __shared__ ushort t[64][65];
  const int b = blockIdx.z;
  const float* Vb  = V  + (long)b * 2048 * 1024;
  ushort*      Vtb = Vt + (long)b * 1024 * 2048;
  const int k0 = blockIdx.x * 64, d0 = blockIdx.y * 64;
  const int c  = threadIdx.x & 63;
  const int r4 = threadIdx.x >> 6;
#pragma unroll
  for (int i = 0; i < 64; i += 4)
    t[i + r4][c] = f2bf(Vb[(long)(k0 + i + r4) * 1024 + d0 + c]);
  __syncthreads();
#pragma unroll
  for (int i = 0; i < 64; i += 4)
    Vtb[(long)(d0 + i + r4) * 2048 + k0 + c] = t[c][i + r4];
}

// ---------------------------------------------------------------------------
// Row softmax over 2048 fp32 (in-place, d_out region) + bf16 copy to ws.
// ---------------------------------------------------------------------------
__global__ __launch_bounds__(256)
void softmax_rows(float* __restrict__ S, ushort* __restrict__ Wb)
{
  const long row = blockIdx.x;
  float*  Sr = S  + row * 2048;
  ushort* Wr = Wb + row * 2048;
  const int tid = threadIdx.x;

  float4 a = *(const float4*)(Sr + tid * 4);
  float4 c = *(const float4*)(Sr + 1024 + tid * 4);

  float m = fmaxf(fmaxf(fmaxf(a.x, a.y), fmaxf(a.z, a.w)),
                  fmaxf(fmaxf(c.x, c.y), fmaxf(c.z, c.w)));
#pragma unroll
  for (int off = 32; off > 0; off >>= 1) m = fmaxf(m, __shfl_xor(m, off, 64));

  __shared__ float red[8];
  const int wid = tid >> 6, lane = tid & 63;
  if (lane == 0) red[wid] = m;
  __syncthreads();
  m = fmaxf(fmaxf(red[0], red[1]), fmaxf(red[2], red[3]));

  float e[8];
  e[0] = __expf(a.x - m); e[1] = __expf(a.y - m);
  e[2] = __expf(a.z - m); e[3] = __expf(a.w - m);
  e[4] = __expf(c.x - m); e[5] = __expf(c.y - m);
  e[6] = __expf(c.z - m); e[7] = __expf(c.w - m);
  float s = e[0] + e[1] + e[2] + e[3] + e[4] + e[5] + e[6] + e[7];
#pragma unroll
  for (int off = 32; off > 0; off >>= 1) s += __shfl_xor(s, off, 64);
  if (lane == 0) red[4 + wid] = s;
  __syncthreads();
  s = red[4] + red[5] + red[6] + red[7];

  const float inv = 1.0f / s;
  float4 o0 = make_float4(e[0] * inv, e[1] * inv, e[2] * inv, e[3] * inv);
  float4 o1 = make_float4(e[4] * inv, e[5] * inv, e[6] * inv, e[7] * inv);
  *(float4*)(Sr + tid * 4)        = o0;
  *(float4*)(Sr + 1024 + tid * 4) = o1;
  ushort4 w0, w1;
  w0.x = f2bf(o0.x); w0.y = f2bf(o0.y); w0.z = f2bf(o0.z); w0.w = f2bf(o0.w);
  w1.x = f2bf(o1.x); w1.y = f2bf(o1.y); w1.z = f2bf(o1.z); w1.w = f2bf(o1.w);
  *(ushort4*)(Wr + tid * 4)        = w0;
  *(ushort4*)(Wr + 1024 + tid * 4) = w1;
}

// ---------------------------------------------------------------------------
// Workspace layout. Wb (bf16 attn weights) aliases dead qb/kb region.
// ---------------------------------------------------------------------------
constexpr size_t SZ_XB  = 16384UL * 1024 * 2;        // 32 MiB
constexpr size_t OFF_QB = 0;
constexpr size_t OFF_KB = SZ_XB;
constexpr size_t OFF_WQ = 2 * SZ_XB;                 // 2 MiB
constexpr size_t OFF_WK = OFF_WQ + 1024UL * 1024 * 2;
constexpr size_t OFF_QP = OFF_WK + 1024UL * 1024 * 2;
constexpr size_t OFF_KP = OFF_QP + SZ_XB;
constexpr size_t OFF_VT = OFF_KP + SZ_XB;
constexpr size_t OFF_WB = 0;                          // aliases QB+KB

extern "C" void kernel_launch(void* const* d_in, const int* in_sizes, int n_in,
                              void* d_out, int out_size, void* d_ws, size_t ws_size,
                              hipStream_t stream)
{
  (void)in_sizes; (void)n_in; (void)out_size; (void)ws_size;

  const float* query = (const float*)d_in[0];  // [8,2048,1024]
  const float* key   = (const float*)d_in[1];  // [8,2048,1024]
  const float* value = (const float*)d_in[2];  // [8,2048,1024]
  const int*   mask  = (const int*)d_in[3];    // [8,1,2048]
  const float* Wq    = (const float*)d_in[4];  // [1024,1024]
  const float* Wk    = (const float*)d_in[5];  // [1024,1024]

  float* out_cxt = (float*)d_out;                      // [8,2048,1024]
  float* out_w   = out_cxt + 8L * 2048 * 1024;         // [8,2048,2048]

  char* ws = (char*)d_ws;
  ushort* qb  = (ushort*)(ws + OFF_QB);
  ushort* kb  = (ushort*)(ws + OFF_KB);
  ushort* wqb = (ushort*)(ws + OFF_WQ);
  ushort* wkb = (ushort*)(ws + OFF_WK);
  ushort* Qp  = (ushort*)(ws + OFF_QP);
  ushort* Kp  = (ushort*)(ws + OFF_KP);
  ushort* Vt  = (ushort*)(ws + OFF_VT);
  ushort* Wb  = (ushort*)(ws + OFF_WB);

  // 1) casts + V transpose
  cvt_f32_bf16<<<16384, 256, 0, stream>>>(query, qb, 4194304);
  cvt_f32_bf16<<<16384, 256, 0, stream>>>(key,   kb, 4194304);
  cvt_f32_bf16<<<1024,  256, 0, stream>>>(Wq, wqb, 262144);
  cvt_f32_bf16<<<1024,  256, 0, stream>>>(Wk, wkb, 262144);
  transpose_v<<<dim3(32, 16, 8), 256, 0, stream>>>(value, Vt);

  // 2) projections: [16384,1024] @ [1024,1024]^T -> bf16   (grid 4x64 = 256)
  gemm_bt<0><<<dim3(4, 64, 1), 512, 0, stream>>>(qb, wqb, Qp, nullptr,
                                                 1024, 1024, 0, 0, 0, 0);
  gemm_bt<0><<<dim3(4, 64, 1), 512, 0, stream>>>(kb, wkb, Kp, nullptr,
                                                 1024, 1024, 0, 0, 0, 0);

  // 3) scores: per-batch [2048,1024]@[2048,1024]^T *1/32, masked (grid 8x8x8)
  gemm_bt<1><<<dim3(8, 8, 8), 512, 0, stream>>>(Qp, Kp, out_w, mask,
                                                2048, 1024,
                                                2048L * 1024, 2048L * 1024,
                                                2048L * 2048, 2048);

  // 4) softmax rows (normalizes out_w in place, emits bf16 weights to ws)
  softmax_rows<<<16384, 256, 0, stream>>>(out_w, Wb);

  // 5) ctx: per-batch [2048,2048] @ Vt[1024,2048]^T -> fp32 (grid 4x8x8)
  gemm_bt<2><<<dim3(4, 8, 8), 512, 0, stream>>>(Wb, Vt, out_cxt, nullptr,
                                                1024, 2048,
                                                2048L * 2048, 1024L * 2048,
                                                2048L * 1024, 0);
}

// Round 6
// 614.035 us; speedup vs baseline: 1.1616x; 1.0429x over previous
//
#include <hip/hip_runtime.h>

// ---------------------------------------------------------------------------
// ScaledDotProductAttention: q=x@Wq^T, k=x@Wk^T, S=q@k^T*1/32 (masked),
// softmax fp32, ctx = W@V.
// GEMM: 256x256 tile, BK=64, 8 waves, m201-style 8-phase schedule:
// per-phase {ds_read subtile | stage 1 half-tile | barrier | MFMA | barrier},
// counted vmcnt(4) at phases 4/8 only, XOR-chunk LDS swizzle, setprio,
// XCD-chunked block swizzle.  Interleaved wave mapping: M-frags stride 32,
// N-frags stride 64, so each phase reads exactly one (A-half, B-half).
// ---------------------------------------------------------------------------

typedef __bf16 bf16x8 __attribute__((ext_vector_type(8)));
typedef float  f32x4  __attribute__((ext_vector_type(4)));

#define AS1 __attribute__((address_space(1)))
#define AS3 __attribute__((address_space(3)))

__device__ __forceinline__ ushort f2bf(float f) {
  union { float f; unsigned u; } v; v.f = f;
  unsigned u = v.u;
  unsigned r = (u + 0x7FFFu + ((u >> 16) & 1u)) >> 16;  // RNE
  return (ushort)r;
}

constexpr float SCORE_SCALE = 0.03125f;  // 1/sqrt(1024)

// ---------------------------------------------------------------------------
// C = A @ B^T, A[M,K] bf16 row-major, B[N,K] bf16 row-major.
// MODE 0: C bf16.  MODE 1: C fp32 = acc*SCALE, mask[n]==0 -> -inf.
// MODE 2: C fp32 plain.
// Requires M%256==0, N%256==0, K%128==0 (nt even, niter>=2).
// ---------------------------------------------------------------------------
template <int MODE>
__global__ __launch_bounds__(512, 2)
void gemm_bt(const ushort* __restrict__ Ag, const ushort* __restrict__ Bg,
             void* __restrict__ Cv, const int* __restrict__ mask,
             int N, int K, long sA, long sB, long sC, int sMask)
{
  // half-tile buffers: [dbuf(tile&1)][half][128*64]
  __shared__ ushort As[2][2][8192];   // 64 KiB
  __shared__ ushort Bs[2][2][8192];   // 64 KiB

  // ---- T1: XCD-chunked bijective block swizzle (all grids have nwg%8==0)
  const int nx = gridDim.x, ny = gridDim.y, nz = gridDim.z;
  const long nwg = (long)nx * ny * nz;
  long flat = blockIdx.x + (long)nx * (blockIdx.y + (long)ny * blockIdx.z);
  int bx = blockIdx.x, by = blockIdx.y, bz = blockIdx.z;
  if ((nwg & 7) == 0) {
    const long cpx = nwg >> 3;
    flat = (flat & 7) * cpx + (flat >> 3);
    bx = (int)(flat % nx);
    by = (int)((flat / nx) % ny);
    bz = (int)(flat / ((long)nx * ny));
  }
  const int m0 = by * 256;
  const int n0 = bx * 256;

  const ushort* Ab = Ag + (long)bz * sA;
  const ushort* Bb = Bg + (long)bz * sB;

  const int tid  = threadIdx.x;
  const int lane = tid & 63;
  const int wid  = tid >> 6;          // 0..7
  const int wm   = wid >> 2;          // 0..1
  const int wn   = wid & 3;           // 0..3
  const int l15  = lane & 15;
  const int lq   = lane >> 4;         // 0..3

  // staging address precompute: half-tile = 128 rows x 64 cols, 2 loads/thr.
  // load j covers LDS rows j*64 + tid/8, phys chunk tid&7; global logical
  // chunk = (tid&7) ^ (row&7)  (XOR swizzle, involution on read side).
  const int srow = tid >> 3;                 // 0..63
  const int sxor = ((tid & 7) ^ (srow & 7)) * 8;
  long gAoff[2][2], gBoff[2][2];
#pragma unroll
  for (int h = 0; h < 2; ++h)
#pragma unroll
    for (int j = 0; j < 2; ++j) {
      gAoff[h][j] = (long)(m0 + h * 128 + j * 64 + srow) * K + sxor;
      gBoff[h][j] = (long)(n0 + h * 128 + j * 64 + srow) * K + sxor;
    }
  const int ldso0 = wid * 512;               // elements; lanes add 16B each
  const int ldso1 = 4096 + wid * 512;

  // fragment read offsets (elements): rows within a half-buffer
  int arowb[4], browb[2], pc8[2];
#pragma unroll
  for (int i = 0; i < 4; ++i) arowb[i] = (i * 32 + wm * 16 + l15) * 64;
#pragma unroll
  for (int i = 0; i < 2; ++i) browb[i] = (i * 64 + wn * 16 + l15) * 64;
#pragma unroll
  for (int kk = 0; kk < 2; ++kk) pc8[kk] = ((kk * 4 + lq) ^ (lane & 7)) * 8;

  f32x4 acc[8][4];
#pragma unroll
  for (int i = 0; i < 8; ++i)
#pragma unroll
    for (int j = 0; j < 4; ++j) acc[i][j] = (f32x4){0.f, 0.f, 0.f, 0.f};

  bf16x8 af[4][2], bA[2][2], bB[2][2];

#define STAGE_A(T_, H, NB) do { const long ko_ = (long)(T_) * 64;             \
    __builtin_amdgcn_global_load_lds((const AS1 void*)(Ab + gAoff[H][0] + ko_),\
                                     (AS3 void*)(&As[NB][H][ldso0]), 16, 0, 0);\
    __builtin_amdgcn_global_load_lds((const AS1 void*)(Ab + gAoff[H][1] + ko_),\
                                     (AS3 void*)(&As[NB][H][ldso1]), 16, 0, 0);\
  } while (0)
#define STAGE_B(T_, H, NB) do { const long ko_ = (long)(T_) * 64;             \
    __builtin_amdgcn_global_load_lds((const AS1 void*)(Bb + gBoff[H][0] + ko_),\
                                     (AS3 void*)(&Bs[NB][H][ldso0]), 16, 0, 0);\
    __builtin_amdgcn_global_load_lds((const AS1 void*)(Bb + gBoff[H][1] + ko_),\
                                     (AS3 void*)(&Bs[NB][H][ldso1]), 16, 0, 0);\
  } while (0)
#define LD_A(MH, NB) do {                                                     \
    _Pragma("unroll") for (int mi2 = 0; mi2 < 4; ++mi2)                        \
    _Pragma("unroll") for (int kk = 0; kk < 2; ++kk)                           \
      af[mi2][kk] = *(const bf16x8*)(&As[NB][MH][arowb[mi2] + pc8[kk]]);       \
  } while (0)
#define LD_B(DST, NH, NB) do {                                                \
    _Pragma("unroll") for (int ni2 = 0; ni2 < 2; ++ni2)                        \
    _Pragma("unroll") for (int kk = 0; kk < 2; ++kk)                           \
      DST[ni2][kk] = *(const bf16x8*)(&Bs[NB][NH][browb[ni2] + pc8[kk]]);      \
  } while (0)
#define QMFMA(MH, NH, BB) do {                                                \
    __builtin_amdgcn_s_setprio(1);                                             \
    _Pragma("unroll") for (int kk = 0; kk < 2; ++kk)                           \
    _Pragma("unroll") for (int mi2 = 0; mi2 < 4; ++mi2)                        \
    _Pragma("unroll") for (int ni2 = 0; ni2 < 2; ++ni2)                        \
      acc[(MH)*4 + mi2][(NH)*2 + ni2] =                                        \
          __builtin_amdgcn_mfma_f32_16x16x32_bf16(                             \
              af[mi2][kk], BB[ni2][kk], acc[(MH)*4 + mi2][(NH)*2 + ni2],       \
              0, 0, 0);                                                        \
    __builtin_amdgcn_s_setprio(0);                                             \
  } while (0)
#define BARX do { __builtin_amdgcn_sched_barrier(0);                          \
    __builtin_amdgcn_s_barrier(); __builtin_amdgcn_sched_barrier(0); } while (0)

  const int nt    = K >> 6;     // even (K%128==0)
  const int niter = nt >> 1;

  // ---- prologue: tile0 fully + a0(1), b1(1);  vmcnt(4) leaves last 2 ht
  STAGE_A(0, 0, 0); STAGE_B(0, 0, 0); STAGE_B(0, 1, 0); STAGE_A(0, 1, 0);
  STAGE_A(1, 0, 1); STAGE_B(1, 1, 1);
  asm volatile("s_waitcnt vmcnt(4)" ::: "memory");
  BARX;

  for (int it = 0; it < niter; ++it) {
    const int  T  = it * 2;
    const bool pf = (it + 1 < niter);
    // ph1: read a0(T),b0(T); stage a1(T+1)
    LD_A(0, 0); LD_B(bA, 0, 0);
    STAGE_A(T + 1, 1, 1);
    BARX; QMFMA(0, 0, bA); BARX;
    // ph2: read b1(T) (A regs reused); stage b0(T+1)
    LD_B(bB, 1, 0);
    STAGE_B(T + 1, 0, 1);
    BARX; QMFMA(0, 1, bB); BARX;
    // ph3: read a1(T) (B regs reused); stage a0(T+2)
    LD_A(1, 0);
    if (pf) STAGE_A(T + 2, 0, 0);
    BARX; QMFMA(1, 1, bB); BARX;
    // ph4: no ds_reads (regs reused); stage b1(T+2); counted wait
    if (pf) { STAGE_B(T + 2, 1, 0);
              asm volatile("s_waitcnt vmcnt(4)" ::: "memory"); }
    else    { asm volatile("s_waitcnt vmcnt(0)" ::: "memory"); }
    BARX; QMFMA(1, 0, bA); BARX;
    // ph5: read a0(T+1),b0(T+1); stage a1(T+2)
    LD_A(0, 1); LD_B(bA, 0, 1);
    if (pf) STAGE_A(T + 2, 1, 0);
    BARX; QMFMA(0, 0, bA); BARX;
    // ph6: read b1(T+1); stage b0(T+2)
    LD_B(bB, 1, 1);
    if (pf) STAGE_B(T + 2, 0, 0);
    BARX; QMFMA(0, 1, bB); BARX;
    // ph7: read a1(T+1); stage a0(T+3)
    LD_A(1, 1);
    if (pf) STAGE_A(T + 3, 0, 1);
    BARX; QMFMA(1, 1, bB); BARX;
    // ph8: stage b1(T+3); counted wait
    if (pf) { STAGE_B(T + 3, 1, 1);
              asm volatile("s_waitcnt vmcnt(4)" ::: "memory"); }
    BARX; QMFMA(1, 0, bA); BARX;
  }

#undef STAGE_A
#undef STAGE_B
#undef LD_A
#undef LD_B
#undef QMFMA
#undef BARX

  // ---- epilogue. acc[i][j]:
  //   row = m0 + (i>>2)*128 + (i&3)*32 + wm*16 + lq*4 + r
  //   col = n0 + (j>>1)*128 + (j&1)*64 + wn*16 + l15
  const int rbase = lq * 4;
  if constexpr (MODE == 0) {
    ushort* C = (ushort*)Cv + (long)bz * sC;
#pragma unroll
    for (int i = 0; i < 8; ++i) {
      const int r0 = m0 + (i >> 2) * 128 + (i & 3) * 32 + wm * 16 + rbase;
#pragma unroll
      for (int j = 0; j < 4; ++j) {
        const int col = n0 + (j >> 1) * 128 + (j & 1) * 64 + wn * 16 + l15;
#pragma unroll
        for (int r = 0; r < 4; ++r)
          C[(long)(r0 + r) * N + col] = f2bf(acc[i][j][r]);
      }
    }
  } else if constexpr (MODE == 1) {
    float* C = (float*)Cv + (long)bz * sC;
    const int* mb = mask + (long)bz * sMask;
    int coln[4], mk[4];
#pragma unroll
    for (int j = 0; j < 4; ++j) {
      coln[j] = n0 + (j >> 1) * 128 + (j & 1) * 64 + wn * 16 + l15;
      mk[j]   = mb[coln[j]];
    }
    const float ninf = -__builtin_inff();
#pragma unroll
    for (int i = 0; i < 8; ++i) {
      const int r0 = m0 + (i >> 2) * 128 + (i & 3) * 32 + wm * 16 + rbase;
#pragma unroll
      for (int j = 0; j < 4; ++j)
#pragma unroll
        for (int r = 0; r < 4; ++r)
          C[(long)(r0 + r) * N + coln[j]] =
              mk[j] ? acc[i][j][r] * SCORE_SCALE : ninf;
    }
  } else {
    float* C = (float*)Cv + (long)bz * sC;
#pragma unroll
    for (int i = 0; i < 8; ++i) {
      const int r0 = m0 + (i >> 2) * 128 + (i & 3) * 32 + wm * 16 + rbase;
#pragma unroll
      for (int j = 0; j < 4; ++j) {
        const int col = n0 + (j >> 1) * 128 + (j & 1) * 64 + wn * 16 + l15;
#pragma unroll
        for (int r = 0; r < 4; ++r)
          C[(long)(r0 + r) * N + col] = acc[i][j][r];
      }
    }
  }
}

// ---------------------------------------------------------------------------
// fp32 -> bf16 elementwise (float4 in, ushort4 out)
// ---------------------------------------------------------------------------
__global__ __launch_bounds__(256)
void cvt_f32_bf16(const float* __restrict__ in, ushort* __restrict__ out, int n4)
{
  const int i = blockIdx.x * 256 + threadIdx.x;
  if (i >= n4) return;
  float4 v = ((const float4*)in)[i];
  ushort4 o;
  o.x = f2bf(v.x); o.y = f2bf(v.y); o.z = f2bf(v.z); o.w = f2bf(v.w);
  ((ushort4*)out)[i] = o;
}

// ---------------------------------------------------------------------------
// Vt[b][d][k] = bf16(V[b][k][d]); 64x64 LDS tile, pad 65 (conflict-free)
// ---------------------------------------------------------------------------
__global__ __launch_bounds__(256)
void transpose_v(const float* __restrict__ V, ushort* __restrict__ Vt)
{
  __shared__ ushort t[64][65];
  const int b = blockIdx.z;
  const float* Vb  = V  + (long)b * 2048 * 1024;
  ushort*      Vtb = Vt + (long)b * 1024 * 2048;
  const int k0 = blockIdx.x * 64, d0 = blockIdx.y * 64;
  const int c  = threadIdx.x & 63;
  const int r4 = threadIdx.x >> 6;
#pragma unroll
  for (int i = 0; i < 64; i += 4)
    t[i + r4][c] = f2bf(Vb[(long)(k0 + i + r4) * 1024 + d0 + c]);
  __syncthreads();
#pragma unroll
  for (int i = 0; i < 64; i += 4)
    Vtb[(long)(d0 + i + r4) * 2048 + k0 + c] = t[c][i + r4];
}

// ---------------------------------------------------------------------------
// Row softmax over 2048 fp32 (in-place, d_out region) + bf16 copy to ws.
// ---------------------------------------------------------------------------
__global__ __launch_bounds__(256)
void softmax_rows(float* __restrict__ S, ushort* __restrict__ Wb)
{
  const long row = blockIdx.x;
  float*  Sr = S  + row * 2048;
  ushort* Wr = Wb + row * 2048;
  const int tid = threadIdx.x;

  float4 a = *(const float4*)(Sr + tid * 4);
  float4 c = *(const float4*)(Sr + 1024 + tid * 4);

  float m = fmaxf(fmaxf(fmaxf(a.x, a.y), fmaxf(a.z, a.w)),
                  fmaxf(fmaxf(c.x, c.y), fmaxf(c.z, c.w)));
#pragma unroll
  for (int off = 32; off > 0; off >>= 1) m = fmaxf(m, __shfl_xor(m, off, 64));

  __shared__ float red[8];
  const int wid = tid >> 6, lane = tid & 63;
  if (lane == 0) red[wid] = m;
  __syncthreads();
  m = fmaxf(fmaxf(red[0], red[1]), fmaxf(red[2], red[3]));

  float e[8];
  e[0] = __expf(a.x - m); e[1] = __expf(a.y - m);
  e[2] = __expf(a.z - m); e[3] = __expf(a.w - m);
  e[4] = __expf(c.x - m); e[5] = __expf(c.y - m);
  e[6] = __expf(c.z - m); e[7] = __expf(c.w - m);
  float s = e[0] + e[1] + e[2] + e[3] + e[4] + e[5] + e[6] + e[7];
#pragma unroll
  for (int off = 32; off > 0; off >>= 1) s += __shfl_xor(s, off, 64);
  if (lane == 0) red[4 + wid] = s;
  __syncthreads();
  s = red[4] + red[5] + red[6] + red[7];

  const float inv = 1.0f / s;
  float4 o0 = make_float4(e[0] * inv, e[1] * inv, e[2] * inv, e[3] * inv);
  float4 o1 = make_float4(e[4] * inv, e[5] * inv, e[6] * inv, e[7] * inv);
  *(float4*)(Sr + tid * 4)        = o0;
  *(float4*)(Sr + 1024 + tid * 4) = o1;
  ushort4 w0, w1;
  w0.x = f2bf(o0.x); w0.y = f2bf(o0.y); w0.z = f2bf(o0.z); w0.w = f2bf(o0.w);
  w1.x = f2bf(o1.x); w1.y = f2bf(o1.y); w1.z = f2bf(o1.z); w1.w = f2bf(o1.w);
  *(ushort4*)(Wr + tid * 4)        = w0;
  *(ushort4*)(Wr + 1024 + tid * 4) = w1;
}

// ---------------------------------------------------------------------------
// Workspace layout. Wb (bf16 attn weights) aliases dead qb/kb region.
// ---------------------------------------------------------------------------
constexpr size_t SZ_XB  = 16384UL * 1024 * 2;        // 32 MiB
constexpr size_t OFF_QB = 0;
constexpr size_t OFF_KB = SZ_XB;
constexpr size_t OFF_WQ = 2 * SZ_XB;                 // 2 MiB
constexpr size_t OFF_WK = OFF_WQ + 1024UL * 1024 * 2;
constexpr size_t OFF_QP = OFF_WK + 1024UL * 1024 * 2;
constexpr size_t OFF_KP = OFF_QP + SZ_XB;
constexpr size_t OFF_VT = OFF_KP + SZ_XB;
constexpr size_t OFF_WB = 0;                          // aliases QB+KB

extern "C" void kernel_launch(void* const* d_in, const int* in_sizes, int n_in,
                              void* d_out, int out_size, void* d_ws, size_t ws_size,
                              hipStream_t stream)
{
  (void)in_sizes; (void)n_in; (void)out_size; (void)ws_size;

  const float* query = (const float*)d_in[0];  // [8,2048,1024]
  const float* key   = (const float*)d_in[1];  // [8,2048,1024]
  const float* value = (const float*)d_in[2];  // [8,2048,1024]
  const int*   mask  = (const int*)d_in[3];    // [8,1,2048]
  const float* Wq    = (const float*)d_in[4];  // [1024,1024]
  const float* Wk    = (const float*)d_in[5];  // [1024,1024]

  float* out_cxt = (float*)d_out;                      // [8,2048,1024]
  float* out_w   = out_cxt + 8L * 2048 * 1024;         // [8,2048,2048]

  char* ws = (char*)d_ws;
  ushort* qb  = (ushort*)(ws + OFF_QB);
  ushort* kb  = (ushort*)(ws + OFF_KB);
  ushort* wqb = (ushort*)(ws + OFF_WQ);
  ushort* wkb = (ushort*)(ws + OFF_WK);
  ushort* Qp  = (ushort*)(ws + OFF_QP);
  ushort* Kp  = (ushort*)(ws + OFF_KP);
  ushort* Vt  = (ushort*)(ws + OFF_VT);
  ushort* Wb  = (ushort*)(ws + OFF_WB);

  // 1) casts + V transpose
  cvt_f32_bf16<<<16384, 256, 0, stream>>>(query, qb, 4194304);
  cvt_f32_bf16<<<16384, 256, 0, stream>>>(key,   kb, 4194304);
  cvt_f32_bf16<<<1024,  256, 0, stream>>>(Wq, wqb, 262144);
  cvt_f32_bf16<<<1024,  256, 0, stream>>>(Wk, wkb, 262144);
  transpose_v<<<dim3(32, 16, 8), 256, 0, stream>>>(value, Vt);

  // 2) projections: [16384,1024] @ [1024,1024]^T -> bf16   (grid 4x64 = 256)
  gemm_bt<0><<<dim3(4, 64, 1), 512, 0, stream>>>(qb, wqb, Qp, nullptr,
                                                 1024, 1024, 0, 0, 0, 0);
  gemm_bt<0><<<dim3(4, 64, 1), 512, 0, stream>>>(kb, wkb, Kp, nullptr,
                                                 1024, 1024, 0, 0, 0, 0);

  // 3) scores: per-batch [2048,1024]@[2048,1024]^T *1/32, masked (grid 8x8x8)
  gemm_bt<1><<<dim3(8, 8, 8), 512, 0, stream>>>(Qp, Kp, out_w, mask,
                                                2048, 1024,
                                                2048L * 1024, 2048L * 1024,
                                                2048L * 2048, 2048);

  // 4) softmax rows (normalizes out_w in place, emits bf16 weights to ws)
  softmax_rows<<<16384, 256, 0, stream>>>(out_w, Wb);

  // 5) ctx: per-batch [2048,2048] @ Vt[1024,2048]^T -> fp32 (grid 4x8x8)
  gemm_bt<2><<<dim3(4, 8, 8), 512, 0, stream>>>(Wb, Vt, out_cxt, nullptr,
                                                1024, 2048,
                                                2048L * 2048, 1024L * 2048,
                                                2048L * 1024, 0);
}